// Round 3
// baseline (712.003 us; speedup 1.0000x reference)
//
#include <hip/hip_runtime.h>
#include <math.h>

// FCGF_AVG2: per-segment mean of x [4194304, 32] over 512 ragged segments,
// then mean @ W1 + b1 -> BN -> relu -> @ W2 + b2 -> BN  => out [512, 128].
// Memory-bound: 537 MB read of x dominates (~85 us at 6.3 TB/s).
//
// Graph-capture safe: kernel_launch issues ONLY kernel launches on `stream`.
// Deterministic: no float atomics — each split writes a private partial,
// reduced by mean_kernel.

#define EPS 1e-5f
constexpr int B     = 512;  // segments / batch rows
constexpr int C_IN  = 32;
constexpr int F1    = 64;
constexpr int F2    = 128;
constexpr int SPLIT = 8;    // blocks per segment for the streaming sum
constexpr int TPB   = 256;

// ---------------- 1. exclusive scan of lengths -> offs[513] ----------------
__global__ void scan_kernel(const int* __restrict__ len, int* __restrict__ offs) {
    __shared__ int buf[B];
    int t = threadIdx.x;
    buf[t] = len[t];
    __syncthreads();
    for (int off = 1; off < B; off <<= 1) {
        int v = (t >= off) ? buf[t - off] : 0;
        __syncthreads();
        buf[t] += v;
        __syncthreads();
    }
    offs[t + 1] = buf[t];
    if (t == 0) offs[0] = 0;
}

// ---------------- 2. segment partial sums (the memory-bound pass) -------------
// x viewed as float4: each row = 8 float4. Segment starts are row-aligned, so
// float4-start indices are multiples of 8; chunks are rounded to multiples of 8
// so every thread keeps a fixed column-group g = tid % 8 (columns 4g..4g+3).
// Block (seg,part) writes its 32-float partial to partials[(seg*SPLIT+part)*32].
__global__ __launch_bounds__(TPB) void segsum_kernel(const float* __restrict__ x,
                                                     const int* __restrict__ offs,
                                                     float* __restrict__ partials) {
    int seg  = blockIdx.x / SPLIT;
    int part = blockIdx.x % SPLIT;
    int s8 = offs[seg] * 8;        // float4 index of segment start
    int e8 = offs[seg + 1] * 8;    // float4 index of segment end
    int total = e8 - s8;
    int chunk = ((total + SPLIT - 1) / SPLIT + 7) & ~7;  // multiple of 8
    int lo = s8 + part * chunk;
    int hi = min(lo + chunk, e8);

    const float4* __restrict__ x4 = reinterpret_cast<const float4*>(x);
    float4 acc = make_float4(0.f, 0.f, 0.f, 0.f);
    for (int i = lo + (int)threadIdx.x; i < hi; i += TPB) {
        float4 v = x4[i];
        acc.x += v.x; acc.y += v.y; acc.z += v.z; acc.w += v.w;
    }

    __shared__ float red[TPB][4];
    int t = threadIdx.x;
    red[t][0] = acc.x; red[t][1] = acc.y; red[t][2] = acc.z; red[t][3] = acc.w;
    __syncthreads();
    // strides are multiples of 8 -> column-group preserved down to threads 0..7
    for (int st = TPB / 2; st >= 8; st >>= 1) {
        if (t < st) {
            red[t][0] += red[t + st][0];
            red[t][1] += red[t + st][1];
            red[t][2] += red[t + st][2];
            red[t][3] += red[t + st][3];
        }
        __syncthreads();
    }
    if (t < 8) {
        float4* dst = reinterpret_cast<float4*>(partials + (size_t)blockIdx.x * C_IN);
        dst[t] = make_float4(red[t][0], red[t][1], red[t][2], red[t][3]);
    }
}

// ------------- 3. reduce the 8 partials per segment, divide by length ---------
// 16384 elements (512 segs x 32 cols); thread -> one output element.
__global__ __launch_bounds__(B) void mean_kernel(const float* __restrict__ partials,
                                                 const int* __restrict__ len,
                                                 float* __restrict__ means) {
    int idx = blockIdx.x * B + threadIdx.x;     // 32 blocks x 512 threads
    int seg = idx / C_IN;
    int c   = idx % C_IN;
    float s = 0.f;
#pragma unroll
    for (int p = 0; p < SPLIT; ++p)
        s += partials[(size_t)(seg * SPLIT + p) * C_IN + c];
    means[idx] = s / (float)len[seg];
}

// ---------------- 4. FC1 + BatchNorm + ReLU ----------------
// One block per output column (64), one thread per batch row (512).
__global__ __launch_bounds__(B) void fc1_kernel(const float* __restrict__ means,
                                                const float* __restrict__ W1,
                                                const float* __restrict__ b1,
                                                const float* __restrict__ g1,
                                                const float* __restrict__ beta1,
                                                float* __restrict__ h) {
    int col = blockIdx.x;
    int r   = threadIdx.x;
    __shared__ float w[C_IN];
    __shared__ float red[B];
    __shared__ float s_mu, s_rstd;
    if (r < C_IN) w[r] = W1[r * F1 + col];
    __syncthreads();

    const float4* __restrict__ mp = reinterpret_cast<const float4*>(means + (size_t)r * C_IN);
    float dot = 0.f;
#pragma unroll
    for (int k = 0; k < C_IN / 4; ++k) {
        float4 v = mp[k];
        dot += v.x * w[4 * k] + v.y * w[4 * k + 1] + v.z * w[4 * k + 2] + v.w * w[4 * k + 3];
    }
    float s = dot + b1[col];

    red[r] = s;
    __syncthreads();
    for (int st = B / 2; st > 0; st >>= 1) {
        if (r < st) red[r] += red[r + st];
        __syncthreads();
    }
    if (r == 0) s_mu = red[0] * (1.0f / (float)B);
    __syncthreads();

    float d = s - s_mu;
    red[r] = d * d;
    __syncthreads();
    for (int st = B / 2; st > 0; st >>= 1) {
        if (r < st) red[r] += red[r + st];
        __syncthreads();
    }
    if (r == 0) s_rstd = 1.0f / sqrtf(red[0] * (1.0f / (float)B) + EPS);
    __syncthreads();

    float hv = g1[col] * d * s_rstd + beta1[col];
    h[r * F1 + col] = fmaxf(hv, 0.f);
}

// ---------------- 5. FC2 + BatchNorm ----------------
__global__ __launch_bounds__(B) void fc2_kernel(const float* __restrict__ h,
                                                const float* __restrict__ W2,
                                                const float* __restrict__ b2,
                                                const float* __restrict__ g2,
                                                const float* __restrict__ beta2,
                                                float* __restrict__ out) {
    int col = blockIdx.x;
    int r   = threadIdx.x;
    __shared__ float w[F1];
    __shared__ float red[B];
    __shared__ float s_mu, s_rstd;
    if (r < F1) w[r] = W2[r * F2 + col];
    __syncthreads();

    const float4* __restrict__ hp = reinterpret_cast<const float4*>(h + (size_t)r * F1);
    float dot = 0.f;
#pragma unroll
    for (int k = 0; k < F1 / 4; ++k) {
        float4 v = hp[k];
        dot += v.x * w[4 * k] + v.y * w[4 * k + 1] + v.z * w[4 * k + 2] + v.w * w[4 * k + 3];
    }
    float s = dot + b2[col];

    red[r] = s;
    __syncthreads();
    for (int st = B / 2; st > 0; st >>= 1) {
        if (r < st) red[r] += red[r + st];
        __syncthreads();
    }
    if (r == 0) s_mu = red[0] * (1.0f / (float)B);
    __syncthreads();

    float d = s - s_mu;
    red[r] = d * d;
    __syncthreads();
    for (int st = B / 2; st > 0; st >>= 1) {
        if (r < st) red[r] += red[r + st];
        __syncthreads();
    }
    if (r == 0) s_rstd = 1.0f / sqrtf(red[0] * (1.0f / (float)B) + EPS);
    __syncthreads();

    out[r * F2 + col] = g2[col] * d * s_rstd + beta2[col];
}

extern "C" void kernel_launch(void* const* d_in, const int* in_sizes, int n_in,
                              void* d_out, int out_size, void* d_ws, size_t ws_size,
                              hipStream_t stream) {
    const float* x     = (const float*)d_in[0];
    const int*   len   = (const int*)d_in[1];
    const float* W1    = (const float*)d_in[2];
    const float* b1    = (const float*)d_in[3];
    const float* g1    = (const float*)d_in[4];
    const float* beta1 = (const float*)d_in[5];
    const float* W2    = (const float*)d_in[6];
    const float* b2    = (const float*)d_in[7];
    const float* g2    = (const float*)d_in[8];
    const float* beta2 = (const float*)d_in[9];
    float* out = (float*)d_out;

    char*  ws       = (char*)d_ws;
    int*   offs     = (int*)ws;                        // 513 ints
    float* partials = (float*)(ws + 4096);             // [B*SPLIT][C_IN] = 512 KB
    float* means    = partials + (size_t)B * SPLIT * C_IN;  // [B][C_IN] = 64 KB
    float* h        = means + (size_t)B * C_IN;             // [B][F1]   = 128 KB

    scan_kernel<<<1, B, 0, stream>>>(len, offs);
    segsum_kernel<<<B * SPLIT, TPB, 0, stream>>>(x, offs, partials);
    mean_kernel<<<C_IN, B, 0, stream>>>(partials, len, means);
    fc1_kernel<<<F1, B, 0, stream>>>(means, W1, b1, g1, beta1, h);
    fc2_kernel<<<F2, B, 0, stream>>>(h, W2, b2, g2, beta2, out);
}